// Round 10
// baseline (71.896 us; speedup 1.0000x reference)
//
#include <hip/hip_runtime.h>
#include <hip/hip_bf16.h>
#include <math.h>

#define NN 8192
#define DD 64
#define TILES_SYM 2080          // 64*65/2 per symmetric combo (128x128 block tiles)
#define T2B (2*TILES_SYM)       // 4160: end of ZZ region
#define TILES_TOTAL 8256        // 2*2080 + 4096
#define TILES_PER_BLOCK 8
#define NBLOCKS (TILES_TOTAL / TILES_PER_BLOCK)   // 1032
#define NSLOT 32
#define SLOT_STRIDE 16          // floats -> 64B per slot

typedef __bf16 bf16x8 __attribute__((ext_vector_type(8)));
typedef float f32x4 __attribute__((ext_vector_type(4)));

#if defined(__has_builtin)
#if __has_builtin(__builtin_amdgcn_exp2f)
#define EXP2F __builtin_amdgcn_exp2f
#endif
#endif
#ifndef EXP2F
#define EXP2F exp2f
#endif

// ws layout:
//   [0,        1048576)  Xb  bf16 [8192][64]
//   [1048576,  2097152)  Zb  bf16 [8192][64]
//   [2097152, +32768)    na  f32  [8192]   ( = -log2(e) * ||x_i||^2 )
//   [+32768,  +65536)    nb  f32  [8192]
//   [+65536,  +71680)    partial f32 [3*NSLOT*SLOT_STRIDE]

__global__ __launch_bounds__(256) void prep_kernel(
        const float* __restrict__ X, const float* __restrict__ Z,
        __hip_bfloat16* __restrict__ Xb, __hip_bfloat16* __restrict__ Zb,
        float* __restrict__ na, float* __restrict__ nb,
        float* __restrict__ partial) {
    int tid = threadIdx.x;
    int gw = blockIdx.x * 4 + (tid >> 6);
    int lane = tid & 63;
    int r8 = lane >> 3, sub = lane & 7;
    int row = gw * 8 + r8;          // [0, 16384)
    const float* src = (row < NN) ? (X + (size_t)row * DD) : (Z + (size_t)(row - NN) * DD);
    __hip_bfloat16* dst = (row < NN) ? (Xb + (size_t)row * DD) : (Zb + (size_t)(row - NN) * DD);
    const float4* p = (const float4*)(src + sub * 8);
    float4 u = p[0], v = p[1];
    float w[8] = {u.x, u.y, u.z, u.w, v.x, v.y, v.z, v.w};
    unsigned int h[8];
    float s = 0.f;
    #pragma unroll
    for (int r = 0; r < 8; ++r) {
        __hip_bfloat16 b = __float2bfloat16(w[r]);
        h[r] = *(unsigned short*)&b;
        float xr = __bfloat162float(b);
        s = fmaf(xr, xr, s);
    }
    uint4 pk;
    pk.x = h[0] | (h[1] << 16); pk.y = h[2] | (h[3] << 16);
    pk.z = h[4] | (h[5] << 16); pk.w = h[6] | (h[7] << 16);
    *(uint4*)(dst + sub * 8) = pk;
    s += __shfl_xor(s, 1, 64);
    s += __shfl_xor(s, 2, 64);
    s += __shfl_xor(s, 4, 64);
    if (sub == 0) {
        float nv = -1.4426950408889634f * s;
        if (row < NN) na[row] = nv; else nb[row - NN] = nv;
    }
    if (blockIdx.x == 0) {
        for (int i = tid; i < 3 * NSLOT * SLOT_STRIDE; i += 256) partial[i] = 0.f;
    }
}

// R9's structure with the tile loop ROLLED (#pragma unroll 1, 2-tile
// ping-pong body via macro -> static buffer indices). Rationale: the fully
// unrolled 8-tile body is ~58KB of code vs 32KB L1I -> every fetch misses;
// fetch stalls are invisible in VALU/MFMA counters and match the "all pipes
// idle at any occupancy" signature of R2-R9. Body now ~10KB, I$-resident.
__global__ __launch_bounds__(256) void mmd_kernel(
        const __hip_bfloat16* __restrict__ Xbh, const __hip_bfloat16* __restrict__ Zbh,
        const float* __restrict__ na, const float* __restrict__ nb,
        float* __restrict__ partial) {
    int tid = threadIdx.x;
    int wave = tid >> 6, lane = tid & 63;
    int wr = wave >> 1, wc = wave & 1;
    int lm = lane & 15;   // A-frag row / B-frag col / C col (within 16)
    int lk = lane >> 4;   // k-group of 8 / C row group of 4
    __shared__ float wsum[4];
    const float C2 = 2.8853900817779268f;  // 2*log2(e)

    // ---- map block's first tile (once) ----
    int t0 = blockIdx.x * TILES_PER_BLOCK;
    int combo, bi, bj;
    if (t0 < T2B) {
        combo = (t0 < TILES_SYM) ? 0 : 1;
        int tt = (t0 < TILES_SYM) ? t0 : t0 - TILES_SYM;
        int rr = (int)((129.0f - sqrtf(16641.0f - 8.0f * (float)tt)) * 0.5f);
        if (rr < 0) rr = 0;
        while (rr > 0 && rr * (129 - rr) / 2 > tt) --rr;
        while ((rr + 1) * (128 - rr) / 2 <= tt) ++rr;
        bi = rr;
        bj = rr + (tt - rr * (129 - rr) / 2);
    } else {
        combo = 2;
        int rem = t0 - T2B;
        bi = rem >> 6;
        bj = rem & 63;
    }
    const bool sym = (combo != 2);
    const __bf16 *A, *B;
    const float *sa, *sb;
    const __bf16* Xb = (const __bf16*)Xbh;
    const __bf16* Zb = (const __bf16*)Zbh;
    if (combo == 0)      { A = Xb; B = Xb; sa = na; sb = na; }
    else if (combo == 1) { A = Zb; B = Zb; sa = nb; sb = nb; }
    else                 { A = Xb; B = Zb; sa = na; sb = nb; }

    // ---- A fragments + row norms for current bi ----
    bf16x8 af[2][4];
    float nav[4][4], navrtmax[4];
    {
        int row0 = bi * 128 + wr * 64;
        #pragma unroll
        for (int ks = 0; ks < 2; ++ks)
            #pragma unroll
            for (int rt = 0; rt < 4; ++rt)
                af[ks][rt] = *(const bf16x8*)(A + (size_t)(row0 + rt * 16 + lm) * DD + ks * 32 + lk * 8);
        #pragma unroll
        for (int rt = 0; rt < 4; ++rt) {
            #pragma unroll
            for (int r = 0; r < 4; ++r) nav[rt][r] = sa[row0 + rt * 16 + lk * 4 + r];
            navrtmax[rt] = fmaxf(fmaxf(nav[rt][0], nav[rt][1]), fmaxf(nav[rt][2], nav[rt][3]));
        }
    }

    // ---- prefetch B for first tile into buf0 ----
    bf16x8 bufB0[2][4], bufB1[2][4];
    float bufNb0[4], bufNb1[4];
    {
        int col0 = bj * 128 + wc * 64;
        #pragma unroll
        for (int ks = 0; ks < 2; ++ks)
            #pragma unroll
            for (int ct = 0; ct < 4; ++ct)
                bufB0[ks][ct] = *(const bf16x8*)(B + (size_t)(col0 + ct * 16 + lm) * DD + ks * 32 + lk * 8);
        #pragma unroll
        for (int ct = 0; ct < 4; ++ct) bufNb0[ct] = sb[col0 + ct * 16 + lm];
    }

    float lsum = 0.f;

// One tile: prefetch next into NXTB/NXTN (if HV), fence, MFMA from CURB,
// gated epilogue, A-reload on row change. All array indices static.
#define TILE_STEP(CURB, CURN, NXTB, NXTN, HV)                                        \
    {                                                                                \
        bool diag = sym && (bi == bj);                                               \
        float tileScale = (sym && bj > bi) ? 2.f : 1.f;                              \
        int row0 = bi * 128 + wr * 64;                                               \
        int col0 = bj * 128 + wc * 64;                                               \
        int nbi = bi, nbj = bj;                                                      \
        if (HV) {                                                                    \
            nbj = bj + 1;                                                            \
            if (nbj == 64) { nbi = bi + 1; nbj = sym ? nbi : 0; }                    \
            int ncol0 = nbj * 128 + wc * 64;                                         \
            _Pragma("unroll")                                                        \
            for (int ks = 0; ks < 2; ++ks)                                           \
                for (int ct = 0; ct < 4; ++ct)                                       \
                    NXTB[ks][ct] = *(const bf16x8*)(B + (size_t)(ncol0 + ct * 16 + lm) * DD + ks * 32 + lk * 8); \
            _Pragma("unroll")                                                        \
            for (int ct = 0; ct < 4; ++ct) NXTN[ct] = sb[ncol0 + ct * 16 + lm];      \
        }                                                                            \
        __builtin_amdgcn_sched_barrier(0);                                           \
        f32x4 acc[4][4] = {};                                                        \
        _Pragma("unroll")                                                            \
        for (int ks = 0; ks < 2; ++ks)                                               \
            for (int rt = 0; rt < 4; ++rt)                                           \
                for (int ct = 0; ct < 4; ++ct)                                       \
                    acc[rt][ct] = __builtin_amdgcn_mfma_f32_16x16x32_bf16(           \
                        af[ks][rt], CURB[ks][ct], acc[rt][ct], 0, 0, 0);             \
        _Pragma("unroll")                                                            \
        for (int rt = 0; rt < 4; ++rt) {                                             \
            for (int ct = 0; ct < 4; ++ct) {                                         \
                float fm = fmaxf(fmaxf(acc[rt][ct][0], acc[rt][ct][1]),              \
                                 fmaxf(acc[rt][ct][2], acc[rt][ct][3]));             \
                float fb = fmaf(fm, C2, navrtmax[rt] + CURN[ct]);                    \
                if (__any(fb > -30.f)) {                                             \
                    float base = CURN[ct];                                           \
                    float a0 = fmaf(acc[rt][ct][0], C2, nav[rt][0] + base);          \
                    float a1 = fmaf(acc[rt][ct][1], C2, nav[rt][1] + base);          \
                    float a2 = fmaf(acc[rt][ct][2], C2, nav[rt][2] + base);          \
                    float a3 = fmaf(acc[rt][ct][3], C2, nav[rt][3] + base);          \
                    float e0 = EXP2F(fminf(a0, 0.f));                                \
                    float e1 = EXP2F(fminf(a1, 0.f));                                \
                    float e2 = EXP2F(fminf(a2, 0.f));                                \
                    float e3 = EXP2F(fminf(a3, 0.f));                                \
                    if (diag) {                                                      \
                        int gcol = col0 + ct * 16 + lm;                              \
                        int gr = row0 + rt * 16 + lk * 4;                            \
                        e0 *= (gr + 0 < gcol) ? 2.f : ((gr + 0 == gcol) ? 1.f : 0.f); \
                        e1 *= (gr + 1 < gcol) ? 2.f : ((gr + 1 == gcol) ? 1.f : 0.f); \
                        e2 *= (gr + 2 < gcol) ? 2.f : ((gr + 2 == gcol) ? 1.f : 0.f); \
                        e3 *= (gr + 3 < gcol) ? 2.f : ((gr + 3 == gcol) ? 1.f : 0.f); \
                        lsum += (e0 + e1) + (e2 + e3);                               \
                    } else {                                                         \
                        lsum += tileScale * ((e0 + e1) + (e2 + e3));                 \
                    }                                                                \
                }                                                                    \
            }                                                                        \
        }                                                                            \
        if ((HV) && nbi != bi) {                                                     \
            int nrow0 = nbi * 128 + wr * 64;                                         \
            _Pragma("unroll")                                                        \
            for (int ks = 0; ks < 2; ++ks)                                           \
                for (int rt = 0; rt < 4; ++rt)                                       \
                    af[ks][rt] = *(const bf16x8*)(A + (size_t)(nrow0 + rt * 16 + lm) * DD + ks * 32 + lk * 8); \
            _Pragma("unroll")                                                        \
            for (int rt = 0; rt < 4; ++rt) {                                         \
                for (int r = 0; r < 4; ++r) nav[rt][r] = sa[nrow0 + rt * 16 + lk * 4 + r]; \
                navrtmax[rt] = fmaxf(fmaxf(nav[rt][0], nav[rt][1]), fmaxf(nav[rt][2], nav[rt][3])); \
            }                                                                        \
            __builtin_amdgcn_sched_barrier(0);                                       \
        }                                                                            \
        bi = nbi; bj = nbj;                                                          \
    }

    #pragma unroll 1
    for (int ii = 0; ii < 4; ++ii) {
        TILE_STEP(bufB0, bufNb0, bufB1, bufNb1, true);        // even tile
        TILE_STEP(bufB1, bufNb1, bufB0, bufNb0, (ii < 3));    // odd tile
    }
#undef TILE_STEP

    // ---- single flush, spread over cache-line slots ----
    #pragma unroll
    for (int off = 32; off; off >>= 1) lsum += __shfl_xor(lsum, off, 64);
    if (lane == 0) wsum[wave] = lsum;
    __syncthreads();
    if (tid == 0) {
        float s = (wsum[0] + wsum[1]) + (wsum[2] + wsum[3]);
        int slot = combo * NSLOT + (blockIdx.x & (NSLOT - 1));
        atomicAdd(&partial[slot * SLOT_STRIDE], s);
    }
}

__global__ void final_kernel(const float* __restrict__ partial, float* __restrict__ out) {
    __shared__ float s3[3];
    int tid = threadIdx.x;
    if (tid < 3) s3[tid] = 0.f;
    __syncthreads();
    if (tid < 3 * NSLOT) {
        float v = partial[tid * SLOT_STRIDE];
        atomicAdd(&s3[tid / NSLOT], v);
    }
    __syncthreads();
    if (tid == 0) {
        double inv = 1.0 / ((double)NN * (double)NN * 2.5066282746310002);  // N^2 * sqrt(2*pi)
        double mxx = (double)s3[0] * inv;
        double mzz = (double)s3[1] * inv;
        double mxz = (double)s3[2] * inv;
        double v = log(sqrt(mxx * mzz + 1e-5) / (mxz + 1e-5));
        out[0] = (float)v;
    }
}

extern "C" void kernel_launch(void* const* d_in, const int* in_sizes, int n_in,
                              void* d_out, int out_size, void* d_ws, size_t ws_size,
                              hipStream_t stream) {
    const float* X = (const float*)d_in[0];
    const float* Z = (const float*)d_in[1];
    char* ws = (char*)d_ws;
    __hip_bfloat16* Xb = (__hip_bfloat16*)(ws);
    __hip_bfloat16* Zb = (__hip_bfloat16*)(ws + 1048576);
    float* na = (float*)(ws + 2097152);
    float* nb = (float*)(ws + 2097152 + 32768);
    float* partial = (float*)(ws + 2097152 + 65536);

    hipLaunchKernelGGL(prep_kernel, dim3(512), dim3(256), 0, stream,
                       X, Z, Xb, Zb, na, nb, partial);
    hipLaunchKernelGGL(mmd_kernel, dim3(NBLOCKS), dim3(256), 0, stream, Xb, Zb, na, nb, partial);
    hipLaunchKernelGGL(final_kernel, dim3(1), dim3(128), 0, stream, partial, (float*)d_out);
}

// Round 11
// 43.044 us; speedup vs baseline: 1.6703x; 1.6703x over previous
//
#include <hip/hip_runtime.h>
#include <hip/hip_bf16.h>
#include <math.h>

#define NN 8192
#define DD 64
#define TILES_SYM 2080          // 64*65/2 per symmetric combo (128x128 block tiles)
#define T2B (2*TILES_SYM)       // 4160: end of ZZ region
#define TILES_TOTAL 8256        // 2*2080 + 4096
#define TILES_PER_BLOCK 8
#define NBLOCKS (TILES_TOTAL / TILES_PER_BLOCK)   // 1032
#define NSLOT 32
#define SLOT_STRIDE 16          // floats -> 64B per slot

// Fragment-order layout: panel p = 16 source rows; chunk lane L holds
// row (p*16 + (L&15)), bf16 elems [ks*32 + (L>>4)*8, +8).
// Element offset of chunk: p*1024 + ks*512 + L*8   (bf16 elements)
#define PANEL_ELEMS 1024        // 16 rows * 64 elems

typedef __bf16 bf16x8 __attribute__((ext_vector_type(8)));
typedef float f32x4 __attribute__((ext_vector_type(4)));

#if defined(__has_builtin)
#if __has_builtin(__builtin_amdgcn_exp2f)
#define EXP2F __builtin_amdgcn_exp2f
#endif
#endif
#ifndef EXP2F
#define EXP2F exp2f
#endif

// ws layout:
//   [0,        1048576)  XbF bf16 [512 panels][2 ks][64 lanes][8]  (fragment order)
//   [1048576,  2097152)  ZbF bf16 same
//   [2097152, +32768)    na  f32  [8192]   ( = -log2(e) * ||x_i||^2 )
//   [+32768,  +65536)    nb  f32  [8192]
//   [+65536,  +71680)    partial f32 [3*NSLOT*SLOT_STRIDE]

// One wave per 16-row panel: lane L reads row p*16+(L&15), floats
// [ks*32+(L>>4)*8, +8), converts to bf16, writes chunk at p*1024+ks*512+L*8.
// Writes are lane-contiguous (1KB per wave per ks). Norms: row sum needs
// lanes {lm, lm+16, lm+32, lm+48} -> shfl_xor 16,32.
__global__ __launch_bounds__(256) void prep_kernel(
        const float* __restrict__ X, const float* __restrict__ Z,
        __hip_bfloat16* __restrict__ XbF, __hip_bfloat16* __restrict__ ZbF,
        float* __restrict__ na, float* __restrict__ nb,
        float* __restrict__ partial) {
    int tid = threadIdx.x;
    int gw = blockIdx.x * 4 + (tid >> 6);    // panel index in [0, 1024)
    int lane = tid & 63;
    int lm = lane & 15, lk = lane >> 4;
    const float* src = (gw < 512) ? X : Z;
    __hip_bfloat16* dst = (gw < 512) ? XbF : ZbF;
    float* nrm = (gw < 512) ? na : nb;
    int p = (gw < 512) ? gw : gw - 512;
    int row = p * 16 + lm;

    float s = 0.f;
    #pragma unroll
    for (int ks = 0; ks < 2; ++ks) {
        const float4* q = (const float4*)(src + (size_t)row * DD + ks * 32 + lk * 8);
        float4 u = q[0], v = q[1];
        float w[8] = {u.x, u.y, u.z, u.w, v.x, v.y, v.z, v.w};
        unsigned int h[8];
        #pragma unroll
        for (int r = 0; r < 8; ++r) {
            __hip_bfloat16 b = __float2bfloat16(w[r]);
            h[r] = *(unsigned short*)&b;
            float xr = __bfloat162float(b);
            s = fmaf(xr, xr, s);
        }
        uint4 pk;
        pk.x = h[0] | (h[1] << 16); pk.y = h[2] | (h[3] << 16);
        pk.z = h[4] | (h[5] << 16); pk.w = h[6] | (h[7] << 16);
        *(uint4*)(dst + (size_t)p * PANEL_ELEMS + ks * 512 + lane * 8) = pk;
    }
    s += __shfl_xor(s, 16, 64);
    s += __shfl_xor(s, 32, 64);
    if (lk == 0) nrm[row] = -1.4426950408889634f * s;

    if (blockIdx.x == 0) {
        for (int i = tid; i < 3 * NSLOT * SLOT_STRIDE; i += 256) partial[i] = 0.f;
    }
}

// R9's exact structure (unrolled 8-tile dbuf + sched_barrier fences); only
// the fragment loads changed: fragment-order layout makes every A/B frag
// load a single CONTIGUOUS 1KB transaction (lane L at base + L*16B) instead
// of 16B/lane scattered across 16 rows 128B apart. Tests the theory that the
// scattered pattern's per-line TA cost is the invisible ~60% stall.
__global__ __launch_bounds__(256) void mmd_kernel(
        const __hip_bfloat16* __restrict__ XbFh, const __hip_bfloat16* __restrict__ ZbFh,
        const float* __restrict__ na, const float* __restrict__ nb,
        float* __restrict__ partial) {
    int tid = threadIdx.x;
    int wave = tid >> 6, lane = tid & 63;
    int wr = wave >> 1, wc = wave & 1;
    int lm = lane & 15;   // frag row (within 16) / C col
    int lk = lane >> 4;   // k-group of 8 / C row group of 4
    __shared__ float wsum[4];
    const float C2 = 2.8853900817779268f;  // 2*log2(e)

    // ---- map block's first tile (once) ----
    int t0 = blockIdx.x * TILES_PER_BLOCK;
    int combo, bi, bj;
    if (t0 < T2B) {
        combo = (t0 < TILES_SYM) ? 0 : 1;
        int tt = (t0 < TILES_SYM) ? t0 : t0 - TILES_SYM;
        int rr = (int)((129.0f - sqrtf(16641.0f - 8.0f * (float)tt)) * 0.5f);
        if (rr < 0) rr = 0;
        while (rr > 0 && rr * (129 - rr) / 2 > tt) --rr;
        while ((rr + 1) * (128 - rr) / 2 <= tt) ++rr;
        bi = rr;
        bj = rr + (tt - rr * (129 - rr) / 2);
    } else {
        combo = 2;
        int rem = t0 - T2B;
        bi = rem >> 6;
        bj = rem & 63;
    }
    const bool sym = (combo != 2);
    const __bf16 *A, *B;
    const float *sa, *sb;
    const __bf16* XbF = (const __bf16*)XbFh;
    const __bf16* ZbF = (const __bf16*)ZbFh;
    if (combo == 0)      { A = XbF; B = XbF; sa = na; sb = na; }
    else if (combo == 1) { A = ZbF; B = ZbF; sa = nb; sb = nb; }
    else                 { A = XbF; B = ZbF; sa = na; sb = nb; }

    // ---- A fragments + row norms for current bi ----
    // wave's A rows: panel pA = bi*8 + wr*4 + rt  (rt = 0..3)
    bf16x8 af[2][4];
    float nav[4][4], navrtmax[4];
    {
        int pA = bi * 8 + wr * 4;
        #pragma unroll
        for (int ks = 0; ks < 2; ++ks)
            #pragma unroll
            for (int rt = 0; rt < 4; ++rt)
                af[ks][rt] = *(const bf16x8*)(A + (size_t)(pA + rt) * PANEL_ELEMS + ks * 512 + lane * 8);
        int row0 = bi * 128 + wr * 64;
        #pragma unroll
        for (int rt = 0; rt < 4; ++rt) {
            #pragma unroll
            for (int r = 0; r < 4; ++r) nav[rt][r] = sa[row0 + rt * 16 + lk * 4 + r];
            navrtmax[rt] = fmaxf(fmaxf(nav[rt][0], nav[rt][1]), fmaxf(nav[rt][2], nav[rt][3]));
        }
    }

    // ---- prefetch B for first tile ----
    bf16x8 bufB[2][2][4];   // [buf][ks][ct]
    float bufNb[2][4];
    {
        int pB = bj * 8 + wc * 4;
        #pragma unroll
        for (int ks = 0; ks < 2; ++ks)
            #pragma unroll
            for (int ct = 0; ct < 4; ++ct)
                bufB[0][ks][ct] = *(const bf16x8*)(B + (size_t)(pB + ct) * PANEL_ELEMS + ks * 512 + lane * 8);
        int col0 = bj * 128 + wc * 64;
        #pragma unroll
        for (int ct = 0; ct < 4; ++ct) bufNb[0][ct] = sb[col0 + ct * 16 + lm];
    }

    float lsum = 0.f;

    #pragma unroll
    for (int it = 0; it < TILES_PER_BLOCK; ++it) {
        const int cur = it & 1, nxt = cur ^ 1;
        const bool last = (it + 1 == TILES_PER_BLOCK);
        bool diag = sym && (bi == bj);
        float tileScale = (sym && bj > bi) ? 2.f : 1.f;
        int row0 = bi * 128 + wr * 64;
        int col0 = bj * 128 + wc * 64;

        // next tile coords + B prefetch (independent of current tile's data)
        int nbi = bi, nbj = bj;
        if (!last) {
            nbj = bj + 1;
            if (nbj == 64) { nbi = bi + 1; nbj = sym ? nbi : 0; }
            int npB = nbj * 8 + wc * 4;
            #pragma unroll
            for (int ks = 0; ks < 2; ++ks)
                #pragma unroll
                for (int ct = 0; ct < 4; ++ct)
                    bufB[nxt][ks][ct] = *(const bf16x8*)(B + (size_t)(npB + ct) * PANEL_ELEMS + ks * 512 + lane * 8);
            int ncol0 = nbj * 128 + wc * 64;
            #pragma unroll
            for (int ct = 0; ct < 4; ++ct) bufNb[nxt][ct] = sb[ncol0 + ct * 16 + lm];
        }
        // Fence: prefetch loads must ISSUE here, before the MFMA cluster.
        __builtin_amdgcn_sched_barrier(0);

        // ---- MFMA ----
        f32x4 acc[4][4] = {};
        #pragma unroll
        for (int ks = 0; ks < 2; ++ks)
            #pragma unroll
            for (int rt = 0; rt < 4; ++rt)
                #pragma unroll
                for (int ct = 0; ct < 4; ++ct)
                    acc[rt][ct] = __builtin_amdgcn_mfma_f32_16x16x32_bf16(
                        af[ks][rt], bufB[cur][ks][ct], acc[rt][ct], 0, 0, 0);

        // ---- gated epilogue ----
        #pragma unroll
        for (int rt = 0; rt < 4; ++rt) {
            #pragma unroll
            for (int ct = 0; ct < 4; ++ct) {
                float fm = fmaxf(fmaxf(acc[rt][ct][0], acc[rt][ct][1]),
                                 fmaxf(acc[rt][ct][2], acc[rt][ct][3]));
                float fb = fmaf(fm, C2, navrtmax[rt] + bufNb[cur][ct]);
                if (__any(fb > -30.f)) {
                    float base = bufNb[cur][ct];
                    float a0 = fmaf(acc[rt][ct][0], C2, nav[rt][0] + base);
                    float a1 = fmaf(acc[rt][ct][1], C2, nav[rt][1] + base);
                    float a2 = fmaf(acc[rt][ct][2], C2, nav[rt][2] + base);
                    float a3 = fmaf(acc[rt][ct][3], C2, nav[rt][3] + base);
                    float e0 = EXP2F(fminf(a0, 0.f));
                    float e1 = EXP2F(fminf(a1, 0.f));
                    float e2 = EXP2F(fminf(a2, 0.f));
                    float e3 = EXP2F(fminf(a3, 0.f));
                    if (diag) {
                        int gcol = col0 + ct * 16 + lm;
                        int gr = row0 + rt * 16 + lk * 4;
                        e0 *= (gr + 0 < gcol) ? 2.f : ((gr + 0 == gcol) ? 1.f : 0.f);
                        e1 *= (gr + 1 < gcol) ? 2.f : ((gr + 1 == gcol) ? 1.f : 0.f);
                        e2 *= (gr + 2 < gcol) ? 2.f : ((gr + 2 == gcol) ? 1.f : 0.f);
                        e3 *= (gr + 3 < gcol) ? 2.f : ((gr + 3 == gcol) ? 1.f : 0.f);
                        lsum += (e0 + e1) + (e2 + e3);
                    } else {
                        lsum += tileScale * ((e0 + e1) + (e2 + e3));
                    }
                }
            }
        }

        // ---- row change: reload A (after epilogue consumed nav) ----
        if (!last && nbi != bi) {
            int npA = nbi * 8 + wr * 4;
            #pragma unroll
            for (int ks = 0; ks < 2; ++ks)
                #pragma unroll
                for (int rt = 0; rt < 4; ++rt)
                    af[ks][rt] = *(const bf16x8*)(A + (size_t)(npA + rt) * PANEL_ELEMS + ks * 512 + lane * 8);
            int nrow0 = nbi * 128 + wr * 64;
            #pragma unroll
            for (int rt = 0; rt < 4; ++rt) {
                #pragma unroll
                for (int r = 0; r < 4; ++r) nav[rt][r] = sa[nrow0 + rt * 16 + lk * 4 + r];
                navrtmax[rt] = fmaxf(fmaxf(nav[rt][0], nav[rt][1]), fmaxf(nav[rt][2], nav[rt][3]));
            }
            __builtin_amdgcn_sched_barrier(0);
        }
        bi = nbi; bj = nbj;
    }

    // ---- single flush, spread over cache-line slots ----
    #pragma unroll
    for (int off = 32; off; off >>= 1) lsum += __shfl_xor(lsum, off, 64);
    if (lane == 0) wsum[wave] = lsum;
    __syncthreads();
    if (tid == 0) {
        float s = (wsum[0] + wsum[1]) + (wsum[2] + wsum[3]);
        int slot = combo * NSLOT + (blockIdx.x & (NSLOT - 1));
        atomicAdd(&partial[slot * SLOT_STRIDE], s);
    }
}

__global__ void final_kernel(const float* __restrict__ partial, float* __restrict__ out) {
    __shared__ float s3[3];
    int tid = threadIdx.x;
    if (tid < 3) s3[tid] = 0.f;
    __syncthreads();
    if (tid < 3 * NSLOT) {
        float v = partial[tid * SLOT_STRIDE];
        atomicAdd(&s3[tid / NSLOT], v);
    }
    __syncthreads();
    if (tid == 0) {
        double inv = 1.0 / ((double)NN * (double)NN * 2.5066282746310002);  // N^2 * sqrt(2*pi)
        double mxx = (double)s3[0] * inv;
        double mzz = (double)s3[1] * inv;
        double mxz = (double)s3[2] * inv;
        double v = log(sqrt(mxx * mzz + 1e-5) / (mxz + 1e-5));
        out[0] = (float)v;
    }
}

extern "C" void kernel_launch(void* const* d_in, const int* in_sizes, int n_in,
                              void* d_out, int out_size, void* d_ws, size_t ws_size,
                              hipStream_t stream) {
    const float* X = (const float*)d_in[0];
    const float* Z = (const float*)d_in[1];
    char* ws = (char*)d_ws;
    __hip_bfloat16* XbF = (__hip_bfloat16*)(ws);
    __hip_bfloat16* ZbF = (__hip_bfloat16*)(ws + 1048576);
    float* na = (float*)(ws + 2097152);
    float* nb = (float*)(ws + 2097152 + 32768);
    float* partial = (float*)(ws + 2097152 + 65536);

    hipLaunchKernelGGL(prep_kernel, dim3(256), dim3(256), 0, stream,
                       X, Z, XbF, ZbF, na, nb, partial);
    hipLaunchKernelGGL(mmd_kernel, dim3(NBLOCKS), dim3(256), 0, stream, XbF, ZbF, na, nb, partial);
    hipLaunchKernelGGL(final_kernel, dim3(1), dim3(128), 0, stream, partial, (float*)d_out);
}

// Round 12
// 35.135 us; speedup vs baseline: 2.0463x; 1.2251x over previous
//
#include <hip/hip_runtime.h>
#include <hip/hip_bf16.h>
#include <math.h>

#define NN 8192
#define DD 64
#define TILES_SYM 2080          // 64*65/2 per symmetric combo (128x128 block tiles)
#define T2B (2*TILES_SYM)       // 4160: end of ZZ region
#define TILES_TOTAL 8256        // 2*2080 + 4096
#define TILES_PER_BLOCK 8
#define NBLOCKS (TILES_TOTAL / TILES_PER_BLOCK)   // 1032
#define NSLOT 32
#define SLOT_STRIDE 16          // floats -> 64B per slot

// Fragment-order layout: panel p = 16 source rows; chunk lane L holds
// row (p*16 + (L&15)), bf16 elems [ks*32 + (L>>4)*8, +8).
// Element offset of chunk: p*1024 + ks*512 + L*8   (bf16 elements)
#define PANEL_ELEMS 1024        // 16 rows * 64 elems

typedef __bf16 bf16x8 __attribute__((ext_vector_type(8)));
typedef float f32x4 __attribute__((ext_vector_type(4)));

#if defined(__has_builtin)
#if __has_builtin(__builtin_amdgcn_exp2f)
#define EXP2F __builtin_amdgcn_exp2f
#endif
#endif
#ifndef EXP2F
#define EXP2F exp2f
#endif

// ws layout:
//   [0,        1048576)  XbF bf16 [512 panels][2 ks][64 lanes][8]  (fragment order)
//   [1048576,  2097152)  ZbF bf16 same
//   [2097152, +32768)    na  f32  [8192]   ( = -log2(e) * ||x_i||^2 )
//   [+32768,  +65536)    nb  f32  [8192]
//   [+65536,  +71680)    partial f32 [3*NSLOT*SLOT_STRIDE]

__global__ __launch_bounds__(256) void prep_kernel(
        const float* __restrict__ X, const float* __restrict__ Z,
        __hip_bfloat16* __restrict__ XbF, __hip_bfloat16* __restrict__ ZbF,
        float* __restrict__ na, float* __restrict__ nb,
        float* __restrict__ partial) {
    int tid = threadIdx.x;
    int gw = blockIdx.x * 4 + (tid >> 6);    // panel index in [0, 1024)
    int lane = tid & 63;
    int lm = lane & 15, lk = lane >> 4;
    const float* src = (gw < 512) ? X : Z;
    __hip_bfloat16* dst = (gw < 512) ? XbF : ZbF;
    float* nrm = (gw < 512) ? na : nb;
    int p = (gw < 512) ? gw : gw - 512;
    int row = p * 16 + lm;

    float s = 0.f;
    #pragma unroll
    for (int ks = 0; ks < 2; ++ks) {
        const float4* q = (const float4*)(src + (size_t)row * DD + ks * 32 + lk * 8);
        float4 u = q[0], v = q[1];
        float w[8] = {u.x, u.y, u.z, u.w, v.x, v.y, v.z, v.w};
        unsigned int h[8];
        #pragma unroll
        for (int r = 0; r < 8; ++r) {
            __hip_bfloat16 b = __float2bfloat16(w[r]);
            h[r] = *(unsigned short*)&b;
            float xr = __bfloat162float(b);
            s = fmaf(xr, xr, s);
        }
        uint4 pk;
        pk.x = h[0] | (h[1] << 16); pk.y = h[2] | (h[3] << 16);
        pk.z = h[4] | (h[5] << 16); pk.w = h[6] | (h[7] << 16);
        *(uint4*)(dst + (size_t)p * PANEL_ELEMS + ks * 512 + lane * 8) = pk;
    }
    s += __shfl_xor(s, 16, 64);
    s += __shfl_xor(s, 32, 64);
    if (lk == 0) nrm[row] = -1.4426950408889634f * s;

    if (blockIdx.x == 0) {
        for (int i = tid; i < 3 * NSLOT * SLOT_STRIDE; i += 256) partial[i] = 0.f;
    }
}

// R11's exact structure (fragment-order contiguous loads, unrolled 8-tile
// dbuf, sched_barrier fences) + TWO-LEVEL GATE: one conservative tile-level
// bound (fmax tree over all 64 acc values) -> single s_cbranch for the ~97%
// of tiles that are fully closed, replacing 16 per-frag __any branches whose
// SALU bubbles are invisible to VALU/MFMA counters. Open tiles fall into the
// unchanged per-frag gated path.
__global__ __launch_bounds__(256) void mmd_kernel(
        const __hip_bfloat16* __restrict__ XbFh, const __hip_bfloat16* __restrict__ ZbFh,
        const float* __restrict__ na, const float* __restrict__ nb,
        float* __restrict__ partial) {
    int tid = threadIdx.x;
    int wave = tid >> 6, lane = tid & 63;
    int wr = wave >> 1, wc = wave & 1;
    int lm = lane & 15;   // frag row (within 16) / C col
    int lk = lane >> 4;   // k-group of 8 / C row group of 4
    __shared__ float wsum[4];
    const float C2 = 2.8853900817779268f;  // 2*log2(e)

    // ---- map block's first tile (once) ----
    int t0 = blockIdx.x * TILES_PER_BLOCK;
    int combo, bi, bj;
    if (t0 < T2B) {
        combo = (t0 < TILES_SYM) ? 0 : 1;
        int tt = (t0 < TILES_SYM) ? t0 : t0 - TILES_SYM;
        int rr = (int)((129.0f - sqrtf(16641.0f - 8.0f * (float)tt)) * 0.5f);
        if (rr < 0) rr = 0;
        while (rr > 0 && rr * (129 - rr) / 2 > tt) --rr;
        while ((rr + 1) * (128 - rr) / 2 <= tt) ++rr;
        bi = rr;
        bj = rr + (tt - rr * (129 - rr) / 2);
    } else {
        combo = 2;
        int rem = t0 - T2B;
        bi = rem >> 6;
        bj = rem & 63;
    }
    const bool sym = (combo != 2);
    const __bf16 *A, *B;
    const float *sa, *sb;
    const __bf16* XbF = (const __bf16*)XbFh;
    const __bf16* ZbF = (const __bf16*)ZbFh;
    if (combo == 0)      { A = XbF; B = XbF; sa = na; sb = na; }
    else if (combo == 1) { A = ZbF; B = ZbF; sa = nb; sb = nb; }
    else                 { A = XbF; B = ZbF; sa = na; sb = nb; }

    // ---- A fragments + row norms for current bi ----
    bf16x8 af[2][4];
    float nav[4][4], navrtmax[4], navmax;
    {
        int pA = bi * 8 + wr * 4;
        #pragma unroll
        for (int ks = 0; ks < 2; ++ks)
            #pragma unroll
            for (int rt = 0; rt < 4; ++rt)
                af[ks][rt] = *(const bf16x8*)(A + (size_t)(pA + rt) * PANEL_ELEMS + ks * 512 + lane * 8);
        int row0 = bi * 128 + wr * 64;
        #pragma unroll
        for (int rt = 0; rt < 4; ++rt) {
            #pragma unroll
            for (int r = 0; r < 4; ++r) nav[rt][r] = sa[row0 + rt * 16 + lk * 4 + r];
            navrtmax[rt] = fmaxf(fmaxf(nav[rt][0], nav[rt][1]), fmaxf(nav[rt][2], nav[rt][3]));
        }
        navmax = fmaxf(fmaxf(navrtmax[0], navrtmax[1]), fmaxf(navrtmax[2], navrtmax[3]));
    }

    // ---- prefetch B for first tile ----
    bf16x8 bufB[2][2][4];   // [buf][ks][ct]
    float bufNb[2][4];
    {
        int pB = bj * 8 + wc * 4;
        #pragma unroll
        for (int ks = 0; ks < 2; ++ks)
            #pragma unroll
            for (int ct = 0; ct < 4; ++ct)
                bufB[0][ks][ct] = *(const bf16x8*)(B + (size_t)(pB + ct) * PANEL_ELEMS + ks * 512 + lane * 8);
        int col0 = bj * 128 + wc * 64;
        #pragma unroll
        for (int ct = 0; ct < 4; ++ct) bufNb[0][ct] = sb[col0 + ct * 16 + lm];
    }

    float lsum = 0.f;

    #pragma unroll
    for (int it = 0; it < TILES_PER_BLOCK; ++it) {
        const int cur = it & 1, nxt = cur ^ 1;
        const bool last = (it + 1 == TILES_PER_BLOCK);
        bool diag = sym && (bi == bj);
        float tileScale = (sym && bj > bi) ? 2.f : 1.f;
        int row0 = bi * 128 + wr * 64;
        int col0 = bj * 128 + wc * 64;

        // next tile coords + B prefetch (independent of current tile's data)
        int nbi = bi, nbj = bj;
        if (!last) {
            nbj = bj + 1;
            if (nbj == 64) { nbi = bi + 1; nbj = sym ? nbi : 0; }
            int npB = nbj * 8 + wc * 4;
            #pragma unroll
            for (int ks = 0; ks < 2; ++ks)
                #pragma unroll
                for (int ct = 0; ct < 4; ++ct)
                    bufB[nxt][ks][ct] = *(const bf16x8*)(B + (size_t)(npB + ct) * PANEL_ELEMS + ks * 512 + lane * 8);
            int ncol0 = nbj * 128 + wc * 64;
            #pragma unroll
            for (int ct = 0; ct < 4; ++ct) bufNb[nxt][ct] = sb[ncol0 + ct * 16 + lm];
        }
        // Fence: prefetch loads must ISSUE here, before the MFMA cluster.
        __builtin_amdgcn_sched_barrier(0);

        // ---- MFMA ----
        f32x4 acc[4][4] = {};
        #pragma unroll
        for (int ks = 0; ks < 2; ++ks)
            #pragma unroll
            for (int rt = 0; rt < 4; ++rt)
                #pragma unroll
                for (int ct = 0; ct < 4; ++ct)
                    acc[rt][ct] = __builtin_amdgcn_mfma_f32_16x16x32_bf16(
                        af[ks][rt], bufB[cur][ks][ct], acc[rt][ct], 0, 0, 0);

        // ---- tile-level gate: one branch for fully-closed tiles ----
        float gmax = fmaxf(fmaxf(acc[0][0][0], acc[0][0][1]), fmaxf(acc[0][0][2], acc[0][0][3]));
        #pragma unroll
        for (int rt = 0; rt < 4; ++rt)
            #pragma unroll
            for (int ct = 0; ct < 4; ++ct)
                if (rt || ct) {
                    float m = fmaxf(fmaxf(acc[rt][ct][0], acc[rt][ct][1]),
                                    fmaxf(acc[rt][ct][2], acc[rt][ct][3]));
                    gmax = fmaxf(gmax, m);
                }
        float nbmax = fmaxf(fmaxf(bufNb[cur][0], bufNb[cur][1]), fmaxf(bufNb[cur][2], bufNb[cur][3]));
        float tileBound = fmaf(gmax, C2, navmax + nbmax);
        if (__any(tileBound > -30.f)) {
            // ---- per-frag gated epilogue (rare: diag-adjacent tiles) ----
            #pragma unroll
            for (int rt = 0; rt < 4; ++rt) {
                #pragma unroll
                for (int ct = 0; ct < 4; ++ct) {
                    float fm = fmaxf(fmaxf(acc[rt][ct][0], acc[rt][ct][1]),
                                     fmaxf(acc[rt][ct][2], acc[rt][ct][3]));
                    float fb = fmaf(fm, C2, navrtmax[rt] + bufNb[cur][ct]);
                    if (__any(fb > -30.f)) {
                        float base = bufNb[cur][ct];
                        float a0 = fmaf(acc[rt][ct][0], C2, nav[rt][0] + base);
                        float a1 = fmaf(acc[rt][ct][1], C2, nav[rt][1] + base);
                        float a2 = fmaf(acc[rt][ct][2], C2, nav[rt][2] + base);
                        float a3 = fmaf(acc[rt][ct][3], C2, nav[rt][3] + base);
                        float e0 = EXP2F(fminf(a0, 0.f));
                        float e1 = EXP2F(fminf(a1, 0.f));
                        float e2 = EXP2F(fminf(a2, 0.f));
                        float e3 = EXP2F(fminf(a3, 0.f));
                        if (diag) {
                            int gcol = col0 + ct * 16 + lm;
                            int gr = row0 + rt * 16 + lk * 4;
                            e0 *= (gr + 0 < gcol) ? 2.f : ((gr + 0 == gcol) ? 1.f : 0.f);
                            e1 *= (gr + 1 < gcol) ? 2.f : ((gr + 1 == gcol) ? 1.f : 0.f);
                            e2 *= (gr + 2 < gcol) ? 2.f : ((gr + 2 == gcol) ? 1.f : 0.f);
                            e3 *= (gr + 3 < gcol) ? 2.f : ((gr + 3 == gcol) ? 1.f : 0.f);
                            lsum += (e0 + e1) + (e2 + e3);
                        } else {
                            lsum += tileScale * ((e0 + e1) + (e2 + e3));
                        }
                    }
                }
            }
        }

        // ---- row change: reload A (after epilogue consumed nav) ----
        if (!last && nbi != bi) {
            int npA = nbi * 8 + wr * 4;
            #pragma unroll
            for (int ks = 0; ks < 2; ++ks)
                #pragma unroll
                for (int rt = 0; rt < 4; ++rt)
                    af[ks][rt] = *(const bf16x8*)(A + (size_t)(npA + rt) * PANEL_ELEMS + ks * 512 + lane * 8);
            int nrow0 = nbi * 128 + wr * 64;
            #pragma unroll
            for (int rt = 0; rt < 4; ++rt) {
                #pragma unroll
                for (int r = 0; r < 4; ++r) nav[rt][r] = sa[nrow0 + rt * 16 + lk * 4 + r];
                navrtmax[rt] = fmaxf(fmaxf(nav[rt][0], nav[rt][1]), fmaxf(nav[rt][2], nav[rt][3]));
            }
            navmax = fmaxf(fmaxf(navrtmax[0], navrtmax[1]), fmaxf(navrtmax[2], navrtmax[3]));
            __builtin_amdgcn_sched_barrier(0);
        }
        bi = nbi; bj = nbj;
    }

    // ---- single flush, spread over cache-line slots ----
    #pragma unroll
    for (int off = 32; off; off >>= 1) lsum += __shfl_xor(lsum, off, 64);
    if (lane == 0) wsum[wave] = lsum;
    __syncthreads();
    if (tid == 0) {
        float s = (wsum[0] + wsum[1]) + (wsum[2] + wsum[3]);
        int slot = combo * NSLOT + (blockIdx.x & (NSLOT - 1));
        atomicAdd(&partial[slot * SLOT_STRIDE], s);
    }
}

__global__ void final_kernel(const float* __restrict__ partial, float* __restrict__ out) {
    __shared__ float s3[3];
    int tid = threadIdx.x;
    if (tid < 3) s3[tid] = 0.f;
    __syncthreads();
    if (tid < 3 * NSLOT) {
        float v = partial[tid * SLOT_STRIDE];
        atomicAdd(&s3[tid / NSLOT], v);
    }
    __syncthreads();
    if (tid == 0) {
        double inv = 1.0 / ((double)NN * (double)NN * 2.5066282746310002);  // N^2 * sqrt(2*pi)
        double mxx = (double)s3[0] * inv;
        double mzz = (double)s3[1] * inv;
        double mxz = (double)s3[2] * inv;
        double v = log(sqrt(mxx * mzz + 1e-5) / (mxz + 1e-5));
        out[0] = (float)v;
    }
}

extern "C" void kernel_launch(void* const* d_in, const int* in_sizes, int n_in,
                              void* d_out, int out_size, void* d_ws, size_t ws_size,
                              hipStream_t stream) {
    const float* X = (const float*)d_in[0];
    const float* Z = (const float*)d_in[1];
    char* ws = (char*)d_ws;
    __hip_bfloat16* XbF = (__hip_bfloat16*)(ws);
    __hip_bfloat16* ZbF = (__hip_bfloat16*)(ws + 1048576);
    float* na = (float*)(ws + 2097152);
    float* nb = (float*)(ws + 2097152 + 32768);
    float* partial = (float*)(ws + 2097152 + 65536);

    hipLaunchKernelGGL(prep_kernel, dim3(256), dim3(256), 0, stream,
                       X, Z, XbF, ZbF, na, nb, partial);
    hipLaunchKernelGGL(mmd_kernel, dim3(NBLOCKS), dim3(256), 0, stream, XbF, ZbF, na, nb, partial);
    hipLaunchKernelGGL(final_kernel, dim3(1), dim3(128), 0, stream, partial, (float*)d_out);
}